// Round 4
// baseline (1088.794 us; speedup 1.0000x reference)
//
#include <hip/hip_runtime.h>
#include <stdint.h>

// SAINT encoder: B=32 S=512 D=512 H=8 DH=64 F=2048 L=4
#define B_ 32
#define S_ 512
#define D_ 512
#define H_ 8
#define F_ 2048
#define L_ 4
#define DH_ 64
#define M_ (B_*S_)

typedef unsigned short u16;
typedef float f32x4 __attribute__((ext_vector_type(4)));
typedef short bf16x8 __attribute__((ext_vector_type(8)));

__device__ __forceinline__ u16 f2b(float f) {
  unsigned u = __float_as_uint(f);
  u += 0x7FFFu + ((u >> 16) & 1u);
  return (u16)(u >> 16);
}
__device__ __forceinline__ float b2f(u16 u) {
  return __uint_as_float((unsigned)u << 16);
}
__device__ __forceinline__ void gld16(const void* g, void* l) {
  __builtin_amdgcn_global_load_lds((__attribute__((address_space(1))) void*)(void*)g,
                                   (__attribute__((address_space(3))) void*)l, 16, 0, 0);
}
__device__ __forceinline__ f32x4 mfma16(bf16x8 a, bf16x8 b, f32x4 c) {
  return __builtin_amdgcn_mfma_f32_16x16x32_bf16(a, b, c, 0, 0, 0);
}
// tanh-form GELU (max |err| ~3e-3 vs erf form; renormalized downstream by Wf+LN)
__device__ __forceinline__ float gelu_fast(float x) {
  float z = 0.7978845608028654f * fmaf(0.044715f * x, x * x, x);
  float e = __expf(2.0f * z);
  float t = 1.0f - 2.0f * __builtin_amdgcn_rcpf(e + 1.0f);   // tanh(z)
  return 0.5f * x * (1.0f + t);
}

#define LOG2E 1.4426950408889634f

// ---------------- weight transpose + bf16: W[R][C] f32 -> WT[C][R] bf16 -----------
__global__ __launch_bounds__(256) void transpose_w(const float* __restrict__ in,
                                                   u16* __restrict__ out, int R, int C) {
  __shared__ float tile[32][33];
  const int l = blockIdx.z;
  in  += (size_t)l * R * C;
  out += (size_t)l * R * C;
  const int c0 = blockIdx.x * 32, r0 = blockIdx.y * 32;
  const int tx = threadIdx.x, ty = threadIdx.y;
#pragma unroll
  for (int k = 0; k < 4; k++)
    tile[ty + 8*k][tx] = in[(size_t)(r0 + ty + 8*k) * C + c0 + tx];
  __syncthreads();
#pragma unroll
  for (int k = 0; k < 4; k++)
    out[(size_t)(c0 + ty + 8*k) * R + r0 + tx] = f2b(tile[tx][ty + 8*k]);
}

// ---------------- x init: bf16 only (f32 output written by final LN) --------------
__global__ __launch_bounds__(256) void prep_x(const float* __restrict__ h,
                                              u16* __restrict__ xb) {
  int i = blockIdx.x * 256 + threadIdx.x;
  float4 v = ((const float4*)h)[i];
  ushort4 u; u.x = f2b(v.x); u.y = f2b(v.y); u.z = f2b(v.z); u.w = f2b(v.w);
  ((ushort4*)xb)[i] = u;
}

// ---------------- pbias f32 -> bf16 * log2e, INTERLEAVED per 64-block -------------
// Layout within each row's 64-col block: pos n = (c&15)*4 + (c>>4)  (c = col&63).
// attn reads the 4 jt values for (row, lr) as ONE ds_read_b64 at n = lr*4.
__global__ __launch_bounds__(256) void prep_pb(const float* __restrict__ pb,
                                               u16* __restrict__ out) {
  const int n0 = (blockIdx.x * 256 + threadIdx.x) * 4;   // output quad base
  const int rowbase = (n0 >> 9) << 9;                    // row * 512
  const int nb = n0 & 511;
  const int blk = (nb >> 6) << 6;                        // 64-block base
  const int lr_ = (nb >> 2) & 15;
  const float* src = pb + rowbase + blk + lr_;
  ushort4 o;
  o.x = f2b(src[0]  * LOG2E);
  o.y = f2b(src[16] * LOG2E);
  o.z = f2b(src[32] * LOG2E);
  o.w = f2b(src[48] * LOG2E);
  ((ushort4*)out)[n0 >> 2] = o;
}

// ---------------- lag-scale table: inv2[b][i][j] = (lag+1)/(9lag+8)*log2e ---------
// Same interleaved layout as prep_pb. u16 fixed-point: enc=round((inv2-0.16)*2^19);
// inv2 in [0.1603, 0.1804] -> enc in [157, 10663], quantization ~3e-5 relative.
__global__ __launch_bounds__(256) void prep_inv(const int* __restrict__ ts,
                                                u16* __restrict__ invb) {
  const int b  = blockIdx.x >> 7;        // grid = B*S/4
  const int rg = blockIdx.x & 127;
  const int wid = threadIdx.x >> 6, lane = threadIdx.x & 63;
  const int i = rg * 4 + wid;
  const float ti = (float)ts[b*S_ + i];
  const int nblk = (lane >> 3) * 64;     // 64-block base of this lane's 8 outputs
  const int l8   = (lane & 7) * 8;       // within-block offset base
  u16 o[8];
#pragma unroll
  for (int e = 0; e < 8; e++) {
    const int no = l8 + e;                                 // 0..63 within block
    const int j  = nblk + (no & 3) * 16 + ((no >> 2) & 15);
    float lag = fmaxf((ti - (float)ts[b*S_ + j]) * (1.0f/60000.0f), 0.0f);
    float iv  = (lag + 1.0f) * __builtin_amdgcn_rcpf(fmaf(lag, 9.0f, 8.0f)) * LOG2E;
    o[e] = (u16)(int)rintf((iv - 0.16f) * 524288.0f);
  }
  ushort4 w0 = {o[0], o[1], o[2], o[3]}, w1 = {o[4], o[5], o[6], o[7]};
  u16* out = invb + (((size_t)(b*S_ + i)) << 9) + lane*8;
  *(ushort4*)out       = w0;
  *(ushort4*)(out + 4) = w1;
}

// ---------------- GEMM 128x128 tile, BK=64, 2-PHASE double-buffered ---------------
// Static dbuf (As0/Bs0, As1/Bs1): issue next tile's global_load_lds BEFORE the
// ds_read+MFMA of the current tile; ONE __syncthreads per tile (its vmcnt(0)
// covers the staged writes, the barrier covers the read-before-overwrite hazard).
// NT = K/64 is even at every call site (8 or 32), so the 2x-unrolled loop is exact.
// B-columns staged PERMUTED (LDS row 16b+a <- global col 4a+b within 64-blocks)
// so fragment (j,lr) holds col wn+lr*4+j -> ushort4/float4 epilogue.
// epi: 0 = bf16 (+bias); 2 = bf16 gelu(+bias); 3 = bf16 V-transposed [B,H,DH,S]
__device__ __forceinline__ void gemm_core(
    const u16* __restrict__ A, const u16* __restrict__ BT,
    const int N, const int K,
    const float* __restrict__ bias, u16* __restrict__ outb, const int epi)
{
  __shared__ u16 As0[128*64], Bs0[128*64];
  __shared__ u16 As1[128*64], Bs1[128*64];
  const int tid = threadIdx.x;
  const int wid = tid >> 6, lane = tid & 63;
  const int wm = (wid >> 1) * 64, wn = (wid & 1) * 64;
  const int lr = lane & 15, quad = lane >> 4;
  const int m0 = blockIdx.x * 128, n0 = blockIdx.y * 128;
  const int l7 = lane & 7, l3 = lane >> 3;
  const int cc = (l7 ^ l3) * 8;          // swizzled staged col offset (u16)
  const int f8 = lr & 7;                 // read swizzle factor

  f32x4 acc[4][4];
#pragma unroll
  for (int i = 0; i < 4; i++)
#pragma unroll
    for (int j = 0; j < 4; j++) acc[i][j] = (f32x4){0.f, 0.f, 0.f, 0.f};

  const u16* Ag = A  + (size_t)(m0 + wid*16 + l3)*K + cc;
  const u16* Bg = BT + (size_t)(n0 + l3*4 + wid)*K + cc;   // permuted source row
  const int wo = wid * 1024;

  auto STAGE = [&](int k0, u16* AsB, u16* BsB) {
    u16* AsW = AsB + wo;
    u16* BsW = BsB + wo;
    gld16(Ag + k0,                 AsW);
    gld16(Ag + (size_t)8*K + k0,   AsW + 512);
    gld16(Ag + (size_t)64*K + k0,  AsW + 4096);
    gld16(Ag + (size_t)72*K + k0,  AsW + 4608);
    gld16(Bg + k0,                 BsW);
    gld16(Bg + (size_t)32*K + k0,  BsW + 512);
    gld16(Bg + (size_t)64*K + k0,  BsW + 4096);
    gld16(Bg + (size_t)96*K + k0,  BsW + 4608);
  };
  auto COMPUTE = [&](const u16* AsB, const u16* BsB) {
#pragma unroll
    for (int kh = 0; kh < 2; kh++) {
      bf16x8 af[4], bfr[4];
#pragma unroll
      for (int i = 0; i < 4; i++)
        af[i]  = *(const bf16x8*)(AsB + (wm + i*16 + lr)*64 + (((kh*4 + quad) ^ f8) * 8));
#pragma unroll
      for (int j = 0; j < 4; j++)
        bfr[j] = *(const bf16x8*)(BsB + (wn + j*16 + lr)*64 + (((kh*4 + quad) ^ f8) * 8));
#pragma unroll
      for (int i = 0; i < 4; i++)
#pragma unroll
        for (int j = 0; j < 4; j++)
          acc[i][j] = mfma16(af[i], bfr[j], acc[i][j]);
    }
  };

  const int NT = K >> 6;                 // even (8 or 32)
  STAGE(0, As0, Bs0);
  __syncthreads();
  for (int t = 0; t < NT; t += 2) {
    STAGE((t + 1) << 6, As1, Bs1);       // prefetch overlaps COMPUTE(buf0)
    COMPUTE(As0, Bs0);
    __syncthreads();                     // vmcnt(0): buf1 ready; buf0 free
    if (t + 2 < NT) STAGE((t + 2) << 6, As0, Bs0);
    COMPUTE(As1, Bs1);
    __syncthreads();
  }

  const int nb = n0 + wn + lr*4;          // lane's 4 contiguous output columns
  float4 b4 = *(const float4*)(bias + nb);
  float bn[4] = {b4.x, b4.y, b4.z, b4.w};

  if (epi == 3) {
#pragma unroll
    for (int i = 0; i < 4; i++) {
      const int m = m0 + wm + i*16 + quad*4;     // sr base; r spans +0..3
      const int bb_ = m >> 9, sr = m & 511;
#pragma unroll
      for (int j = 0; j < 4; j++) {
        const int n = nb + j;
        const int hh = n >> 6, dd = n & 63;
        ushort4 o;
        o.x = f2b(acc[i][j][0] + bn[j]);
        o.y = f2b(acc[i][j][1] + bn[j]);
        o.z = f2b(acc[i][j][2] + bn[j]);
        o.w = f2b(acc[i][j][3] + bn[j]);
        *(ushort4*)(outb + (((size_t)((bb_*H_ + hh)*DH_ + dd)) << 9) + sr) = o;
      }
    }
  } else if (epi == 2) {
#pragma unroll
    for (int i = 0; i < 4; i++) {
#pragma unroll
      for (int r = 0; r < 4; r++) {
        const size_t m = (size_t)(m0 + wm + i*16 + quad*4 + r);
        ushort4 o;
        o.x = f2b(gelu_fast(acc[i][0][r] + bn[0]));
        o.y = f2b(gelu_fast(acc[i][1][r] + bn[1]));
        o.z = f2b(gelu_fast(acc[i][2][r] + bn[2]));
        o.w = f2b(gelu_fast(acc[i][3][r] + bn[3]));
        *(ushort4*)(outb + m*N + nb) = o;
      }
    }
  } else {
#pragma unroll
    for (int i = 0; i < 4; i++) {
#pragma unroll
      for (int r = 0; r < 4; r++) {
        const size_t m = (size_t)(m0 + wm + i*16 + quad*4 + r);
        ushort4 o;
        o.x = f2b(acc[i][0][r] + bn[0]);
        o.y = f2b(acc[i][1][r] + bn[1]);
        o.z = f2b(acc[i][2][r] + bn[2]);
        o.w = f2b(acc[i][3][r] + bn[3]);
        *(ushort4*)(outb + m*N + nb) = o;
      }
    }
  }
}

__global__ __launch_bounds__(256) void gemm_kernel(
    const u16* A, const u16* BT, int N, int K,
    const float* bias, u16* outb, int epi)
{
  gemm_core(A, BT, N, K, bias, outb, epi);
}

__global__ __launch_bounds__(256) void gemm_qkv_kernel(
    const u16* A, const u16* BTq, size_t zstride, int K,
    const float* b0, const float* b1, const float* b2,
    u16* out0, u16* out1, u16* out2)
{
  const int z = blockIdx.z;
  const u16* BT = BTq + (size_t)z * zstride;
  const float* bias = (z == 0) ? b0 : (z == 1) ? b1 : b2;
  u16* outb = (z == 0) ? out0 : (z == 1) ? out1 : out2;
  gemm_core(A, BT, 512, K, bias, outb, (z == 2) ? 3 : 0);
}

// ---------------- GEMM 64x128 tile, BK=64, 2-PHASE dbuf (Wo / Wf) -----------------
// f32 out + bias + bf16 residual. Same pipeline structure as gemm_core.
__global__ __launch_bounds__(256) void gemm64_kernel(
    const u16* __restrict__ A, const u16* __restrict__ BT,
    const int N, const int K,
    const float* __restrict__ bias, const u16* __restrict__ resb,
    float* __restrict__ outf)
{
  __shared__ u16 As0[64*64], Bs0[128*64];
  __shared__ u16 As1[64*64], Bs1[128*64];
  const int tid = threadIdx.x;
  const int wid = tid >> 6, lane = tid & 63;
  const int wm = (wid >> 1) * 32, wn = (wid & 1) * 64;
  const int lr = lane & 15, quad = lane >> 4;
  const int m0 = blockIdx.x * 64, n0 = blockIdx.y * 128;
  const int l7 = lane & 7, l3 = lane >> 3;
  const int cc = (l7 ^ l3) * 8;
  const int f8 = lr & 7;

  f32x4 acc[2][4];
#pragma unroll
  for (int i = 0; i < 2; i++)
#pragma unroll
    for (int j = 0; j < 4; j++) acc[i][j] = (f32x4){0.f, 0.f, 0.f, 0.f};

  const u16* Ag = A  + (size_t)(m0 + wid*8 + l3)*K + cc;
  const u16* Bg = BT + (size_t)(n0 + l3*4 + wid)*K + cc;   // permuted source row

  auto STAGE = [&](int k0, u16* AsB, u16* BsB) {
    u16* AsW = AsB + wid*512;
    u16* BsW = BsB + wid*1024;
    gld16(Ag + k0,                AsW);
    gld16(Ag + (size_t)32*K + k0, AsW + 2048);
    gld16(Bg + k0,                 BsW);
    gld16(Bg + (size_t)32*K + k0,  BsW + 512);
    gld16(Bg + (size_t)64*K + k0,  BsW + 4096);
    gld16(Bg + (size_t)96*K + k0,  BsW + 4608);
  };
  auto COMPUTE = [&](const u16* AsB, const u16* BsB) {
#pragma unroll
    for (int kh = 0; kh < 2; kh++) {
      bf16x8 af[2], bfr[4];
#pragma unroll
      for (int i = 0; i < 2; i++)
        af[i]  = *(const bf16x8*)(AsB + (wm + i*16 + lr)*64 + (((kh*4 + quad) ^ f8) * 8));
#pragma unroll
      for (int j = 0; j < 4; j++)
        bfr[j] = *(const bf16x8*)(BsB + (wn + j*16 + lr)*64 + (((kh*4 + quad) ^ f8) * 8));
#pragma unroll
      for (int i = 0; i < 2; i++)
#pragma unroll
        for (int j = 0; j < 4; j++)
          acc[i][j] = mfma16(af[i], bfr[j], acc[i][j]);
    }
  };

  const int NT = K >> 6;                 // even (8 or 32)
  STAGE(0, As0, Bs0);
  __syncthreads();
  for (int t = 0; t < NT; t += 2) {
    STAGE((t + 1) << 6, As1, Bs1);
    COMPUTE(As0, Bs0);
    __syncthreads();
    if (t + 2 < NT) STAGE((t + 2) << 6, As0, Bs0);
    COMPUTE(As1, Bs1);
    __syncthreads();
  }

  const int nb = n0 + wn + lr*4;
  float4 b4 = *(const float4*)(bias + nb);
  float bn[4] = {b4.x, b4.y, b4.z, b4.w};

#pragma unroll
  for (int i = 0; i < 2; i++) {
#pragma unroll
    for (int r = 0; r < 4; r++) {
      const size_t m = (size_t)(m0 + wm + i*16 + quad*4 + r);
      ushort4 rq = *(const ushort4*)(resb + m*N + nb);
      float4 ov;
      ov.x = acc[i][0][r] + bn[0] + b2f(rq.x);
      ov.y = acc[i][1][r] + bn[1] + b2f(rq.y);
      ov.z = acc[i][2][r] + bn[2] + b2f(rq.z);
      ov.w = acc[i][3][r] + bn[3] + b2f(rq.w);
      *(float4*)(outf + m*N + nb) = ov;
    }
  }
}

// ---------------- LayerNorm: f32 in; bf16 out + optional f32 out ------------------
__global__ __launch_bounds__(256) void ln_kernel(
    const float* __restrict__ y, const float* __restrict__ g, const float* __restrict__ bta,
    float* __restrict__ outf, u16* __restrict__ outb)
{
  const int lane = threadIdx.x & 63;
  const int row = blockIdx.x*4 + (threadIdx.x >> 6);
  const float* yr = y + (size_t)row*D_ + lane*8;
  float4 a0 = *(const float4*)yr;
  float4 a1 = *(const float4*)(yr + 4);
  float v[8] = {a0.x, a0.y, a0.z, a0.w, a1.x, a1.y, a1.z, a1.w};
  float s = 0.f;
#pragma unroll
  for (int e = 0; e < 8; e++) s += v[e];
#pragma unroll
  for (int m = 1; m < 64; m <<= 1) s += __shfl_xor(s, m);
  const float mu = s * (1.0f/512.0f);
  float q = 0.f;
#pragma unroll
  for (int e = 0; e < 8; e++) { float d = v[e] - mu; q += d*d; }
#pragma unroll
  for (int m = 1; m < 64; m <<= 1) q += __shfl_xor(q, m);
  const float rs = rsqrtf(q * (1.0f/512.0f) + 1e-12f);
  float4 g0 = *(const float4*)(g + lane*8);
  float4 g1 = *(const float4*)(g + lane*8 + 4);
  float4 b0 = *(const float4*)(bta + lane*8);
  float4 b1 = *(const float4*)(bta + lane*8 + 4);
  float gg[8] = {g0.x, g0.y, g0.z, g0.w, g1.x, g1.y, g1.z, g1.w};
  float bb[8] = {b0.x, b0.y, b0.z, b0.w, b1.x, b1.y, b1.z, b1.w};
  float o[8];
#pragma unroll
  for (int e = 0; e < 8; e++) o[e] = (v[e] - mu) * rs * gg[e] + bb[e];
  if (outf) {
    float4 w0 = {o[0], o[1], o[2], o[3]}, w1 = {o[4], o[5], o[6], o[7]};
    *(float4*)(outf + (size_t)row*D_ + lane*8)     = w0;
    *(float4*)(outf + (size_t)row*D_ + lane*8 + 4) = w1;
  }
  ushort4 u0 = {f2b(o[0]), f2b(o[1]), f2b(o[2]), f2b(o[3])};
  ushort4 u1 = {f2b(o[4]), f2b(o[5]), f2b(o[6]), f2b(o[7])};
  *(ushort4*)(outb + (size_t)row*D_ + lane*8)     = u0;
  *(ushort4*)(outb + (size_t)row*D_ + lane*8 + 4) = u1;
}

// ---------------- flash attention; interleaved table b64 reads --------------------
// P exponent: p = 2^(s * inv2 + pb2). inv2/pb2 tables stored INTERLEAVED per
// 64-block (pos n=(c&15)*4+(c>>4)): lane reads its 4 jt values as one ds_read_b64,
// folding the 16B-chunk XOR staging swizzle into the address.
// LDS: 5 x 8KB = 40960 B -> 4 blocks/CU exactly.
__global__ __launch_bounds__(256, 4) void attn_kernel(
    const u16* __restrict__ qb, const u16* __restrict__ kb, const u16* __restrict__ vt,
    const u16* __restrict__ pb16, const u16* __restrict__ invb, u16* __restrict__ cb)
{
  __shared__ u16 QPs[64*64];                 // Q tile; wave's 16-row slice reused as P
  __shared__ u16 Ks[64*64], Vs[64*64], PBs[64*64], INVs[64*64];
  const int b = blockIdx.x, it = blockIdx.y, h = blockIdx.z;
  const int i0 = it * 64;
  const int tid = threadIdx.x, wid = tid >> 6, lane = tid & 63;
  const int lr = lane & 15, quad = lane >> 4;
  const int l7 = lane & 7, l3 = lane >> 3;
  const int cc = (l7 ^ l3) * 8;
  const int f8 = lr & 7;
  const int rr = wid*8 + l3;

  const u16* qg  = qb + ((size_t)(b*S_ + i0))*D_ + h*DH_;
  const u16* kg  = kb + ((size_t)b*S_)*D_ + h*DH_;
  const u16* vg  = vt + ((size_t)(b*H_ + h)*DH_)*S_;
  const u16* pbg = pb16 + ((size_t)(h*S_ + i0))*S_;
  const u16* ivg = invb + ((size_t)(b*S_ + i0))*S_;

  gld16(qg + (size_t)rr*D_ + cc,        QPs + wid*512);
  gld16(qg + (size_t)(rr+32)*D_ + cc,   QPs + 2048 + wid*512);
  __syncthreads();

  bf16x8 aq0 = *(const bf16x8*)(QPs + (wid*16 + lr)*64 + ((quad ^ f8) * 8));
  bf16x8 aq1 = *(const bf16x8*)(QPs + (wid*16 + lr)*64 + (((quad ^ f8) ^ 4) * 8));
  u16* Pw = QPs + wid*1024;

  f32x4 O[4]; float lacc[4];
#pragma unroll
  for (int dt = 0; dt < 4; dt++) O[dt] = (f32x4){0.f, 0.f, 0.f, 0.f};
#pragma unroll
  for (int r = 0; r < 4; r++) lacc[r] = 0.f;
  const int lrh = lr >> 3;

  for (int t8 = 0; t8 < 8; t8++) {
    const int j0 = t8 * 64;
    gld16(kg + (size_t)(j0+rr)*D_ + cc,       Ks   + wid*512);
    gld16(kg + (size_t)(j0+rr+32)*D_ + cc,    Ks   + 2048 + wid*512);
    gld16(vg + (size_t)rr*S_ + j0 + cc,       Vs   + wid*512);
    gld16(vg + (size_t)(rr+32)*S_ + j0 + cc,  Vs   + 2048 + wid*512);
    gld16(pbg + (size_t)rr*S_ + j0 + cc,      PBs  + wid*512);
    gld16(pbg + (size_t)(rr+32)*S_ + j0 + cc, PBs  + 2048 + wid*512);
    gld16(ivg + (size_t)rr*S_ + j0 + cc,      INVs + wid*512);
    gld16(ivg + (size_t)(rr+32)*S_ + j0 + cc, INVs + 2048 + wid*512);
    __syncthreads();

    f32x4 s[4];
#pragma unroll
    for (int jt = 0; jt < 4; jt++) {
      const u16* kr = Ks + (jt*16 + lr)*64;
      bf16x8 bk0 = *(const bf16x8*)(kr + ((quad ^ f8) * 8));
      bf16x8 bk1 = *(const bf16x8*)(kr + (((quad ^ f8) ^ 4) * 8));
      f32x4 z = (f32x4){0.f, 0.f, 0.f, 0.f};
      z = mfma16(aq0, bk0, z);
      z = mfma16(aq1, bk1, z);
      s[jt] = z;
    }
#pragma unroll
    for (int r = 0; r < 4; r++) {
      const int rowl = quad*4 + r;
      const int r7 = rowl & 7;
      // b64 read: chunk (lr>>1) XOR'd with staging row key r7, half lr&1
      const int tbase = (wid*16 + rowl)*64 + ((((lr >> 1) ^ r7) << 3) | ((lr & 1) << 2));
      ushort4 ivq = *(const ushort4*)(INVs + tbase);
      ushort4 pbq = *(const ushort4*)(PBs + tbase);
      const u16 ive[4] = {ivq.x, ivq.y, ivq.z, ivq.w};
      const u16 pbe[4] = {pbq.x, pbq.y, pbq.z, pbq.w};
      const int pbase = rowl*64;
      float pa = 0.f;
#pragma unroll
      for (int jt = 0; jt < 4; jt++) {
        float iv  = fmaf((float)ive[jt], 0x1p-19f, 0.16f);
        float pbf = b2f(pbe[jt]);
        float p = __builtin_amdgcn_exp2f(fmaf(s[jt][r], iv, pbf));
        pa += p;
        const int idx = (((jt*2 + lrh) ^ r7) * 8) + l7;
        Pw[pbase + idx] = f2b(p);
      }
      lacc[r] += pa;
    }
    bf16x8 ap0 = *(const bf16x8*)(Pw + lr*64 + ((quad ^ f8) * 8));
    bf16x8 ap1 = *(const bf16x8*)(Pw + lr*64 + (((quad ^ f8) ^ 4) * 8));
#pragma unroll
    for (int dt = 0; dt < 4; dt++) {
      const u16* vr = Vs + (dt*16 + lr)*64;
      bf16x8 bv0 = *(const bf16x8*)(vr + ((quad ^ f8) * 8));
      bf16x8 bv1 = *(const bf16x8*)(vr + (((quad ^ f8) ^ 4) * 8));
      O[dt] = mfma16(ap0, bv0, O[dt]);
      O[dt] = mfma16(ap1, bv1, O[dt]);
    }
    __syncthreads();
  }

#pragma unroll
  for (int r = 0; r < 4; r++) {
    float sum = lacc[r];
#pragma unroll
    for (int m = 1; m < 16; m <<= 1) sum += __shfl_xor(sum, m);
    const float inv = __builtin_amdgcn_rcpf(sum);
    const size_t row = (size_t)(b*S_ + i0 + wid*16 + quad*4 + r);
#pragma unroll
    for (int dt = 0; dt < 4; dt++)
      cb[row*D_ + h*DH_ + dt*16 + lr] = f2b(O[dt][r] * inv);
  }
}

// ---------------- orchestration ---------------------------------------------------
extern "C" void kernel_launch(void* const* d_in, const int* in_sizes, int n_in,
                              void* d_out, int out_size, void* d_ws, size_t ws_size,
                              hipStream_t stream)
{
  const float* hidden = (const float*)d_in[0];
  const float* pbias  = (const float*)d_in[1];
  const int*   ts     = (const int*)d_in[2];
  const float* Wq = (const float*)d_in[3];   const float* bq  = (const float*)d_in[4];
  const float* Wk = (const float*)d_in[5];   const float* bk  = (const float*)d_in[6];
  const float* Wv = (const float*)d_in[7];   const float* bv  = (const float*)d_in[8];
  const float* Wo = (const float*)d_in[9];   const float* bo  = (const float*)d_in[10];
  const float* l1g = (const float*)d_in[11]; const float* l1b = (const float*)d_in[12];
  const float* Wi = (const float*)d_in[13];  const float* bi  = (const float*)d_in[14];
  const float* Wf = (const float*)d_in[15];  const float* bfw = (const float*)d_in[16];
  const float* l2g = (const float*)d_in[17]; const float* l2b = (const float*)d_in[18];

  char* w = (char*)d_ws;
  u16* xb    = (u16*)w; w += (size_t)M_*D_*2;
  u16* qb    = (u16*)w; w += (size_t)M_*D_*2;
  u16* kbuf  = (u16*)w; w += (size_t)M_*D_*2;
  u16* vtw   = (u16*)w; w += (size_t)M_*D_*2;
  u16* cbuf  = (u16*)w; w += (size_t)M_*D_*2;
  u16* attnb = (u16*)w; w += (size_t)M_*D_*2;
  float* yf  = (float*)w; w += (size_t)M_*D_*4;
  u16* WqkvT = (u16*)w; w += (size_t)3*L_*D_*D_*2;
  u16* WoT   = (u16*)w; w += (size_t)L_*D_*D_*2;
  u16* WiT   = (u16*)w; w += (size_t)L_*D_*F_*2;
  u16* WfT   = (u16*)w; w += (size_t)L_*F_*D_*2;
  u16* pbb   = (u16*)w; w += (size_t)H_*S_*S_*2;
  u16* invb  = (u16*)w; w += (size_t)B_*S_*S_*2;
  u16* hb    = qb;   // alias: qb..cbuf = M_*F_ bf16; lifetimes disjoint

  float* x = (float*)d_out;   // written only by the final ln2

  const size_t WD = (size_t)D_*D_;
  const size_t WF = (size_t)D_*F_;
  dim3 tb(32, 8);

  transpose_w<<<dim3(16,16,L_), tb, 0, stream>>>(Wq, WqkvT,           D_, D_);
  transpose_w<<<dim3(16,16,L_), tb, 0, stream>>>(Wk, WqkvT + L_*WD,   D_, D_);
  transpose_w<<<dim3(16,16,L_), tb, 0, stream>>>(Wv, WqkvT + 2*L_*WD, D_, D_);
  transpose_w<<<dim3(16,16,L_), tb, 0, stream>>>(Wo, WoT,             D_, D_);
  transpose_w<<<dim3(64,16,L_), tb, 0, stream>>>(Wi, WiT,             D_, F_);
  transpose_w<<<dim3(16,64,L_), tb, 0, stream>>>(Wf, WfT,             F_, D_);
  prep_x<<<dim3(8192), dim3(256), 0, stream>>>(hidden, xb);
  prep_pb<<<dim3(H_*S_*S_/1024), dim3(256), 0, stream>>>(pbias, pbb);
  prep_inv<<<dim3(B_*S_/4), dim3(256), 0, stream>>>(ts, invb);

  for (int l = 0; l < L_; l++) {
    gemm_qkv_kernel<<<dim3(128,4,3), dim3(256), 0, stream>>>(
        xb, WqkvT + l*WD, (size_t)L_*WD, D_,
        bq + l*D_, bk + l*D_, bv + l*D_, qb, kbuf, vtw);
    attn_kernel<<<dim3(B_,8,H_), dim3(256), 0, stream>>>(qb, kbuf, vtw, pbb, invb, cbuf);
    gemm64_kernel<<<dim3(256,4), dim3(256), 0, stream>>>(
        cbuf, WoT + l*WD, D_, D_, bo + l*D_, xb, yf);
    ln_kernel<<<dim3(4096), dim3(256), 0, stream>>>(yf, l1g + l*D_, l1b + l*D_,
                                                    (float*)nullptr, attnb);
    gemm_kernel<<<dim3(128,16), dim3(256), 0, stream>>>(
        attnb, WiT + l*WF, F_, D_, bi + l*F_, hb, 2);
    gemm64_kernel<<<dim3(256,4), dim3(256), 0, stream>>>(
        hb, WfT + l*WF, D_, F_, bfw + l*D_, attnb, yf);
    ln_kernel<<<dim3(4096), dim3(256), 0, stream>>>(yf, l2g + l*D_, l2b + l*D_,
                                                    (l == 3) ? x : (float*)nullptr, xb);
  }
}

// Round 5
// 978.939 us; speedup vs baseline: 1.1122x; 1.1122x over previous
//
#include <hip/hip_runtime.h>
#include <stdint.h>

// SAINT encoder: B=32 S=512 D=512 H=8 DH=64 F=2048 L=4
#define B_ 32
#define S_ 512
#define D_ 512
#define H_ 8
#define F_ 2048
#define L_ 4
#define DH_ 64
#define M_ (B_*S_)

typedef unsigned short u16;
typedef float f32x4 __attribute__((ext_vector_type(4)));
typedef short bf16x8 __attribute__((ext_vector_type(8)));

__device__ __forceinline__ u16 f2b(float f) {
  unsigned u = __float_as_uint(f);
  u += 0x7FFFu + ((u >> 16) & 1u);
  return (u16)(u >> 16);
}
__device__ __forceinline__ float b2f(u16 u) {
  return __uint_as_float((unsigned)u << 16);
}
__device__ __forceinline__ void gld16(const void* g, void* l) {
  __builtin_amdgcn_global_load_lds((__attribute__((address_space(1))) void*)(void*)g,
                                   (__attribute__((address_space(3))) void*)l, 16, 0, 0);
}
__device__ __forceinline__ f32x4 mfma16(bf16x8 a, bf16x8 b, f32x4 c) {
  return __builtin_amdgcn_mfma_f32_16x16x32_bf16(a, b, c, 0, 0, 0);
}
// tanh-form GELU (max |err| ~3e-3 vs erf form; renormalized downstream by Wf+LN)
__device__ __forceinline__ float gelu_fast(float x) {
  float z = 0.7978845608028654f * fmaf(0.044715f * x, x * x, x);
  float e = __expf(2.0f * z);
  float t = 1.0f - 2.0f * __builtin_amdgcn_rcpf(e + 1.0f);   // tanh(z)
  return 0.5f * x * (1.0f + t);
}

#define LOG2E 1.4426950408889634f

// ---------------- weight transpose + bf16: W[R][C] f32 -> WT[C][R] bf16 -----------
__global__ __launch_bounds__(256) void transpose_w(const float* __restrict__ in,
                                                   u16* __restrict__ out, int R, int C) {
  __shared__ float tile[32][33];
  const int l = blockIdx.z;
  in  += (size_t)l * R * C;
  out += (size_t)l * R * C;
  const int c0 = blockIdx.x * 32, r0 = blockIdx.y * 32;
  const int tx = threadIdx.x, ty = threadIdx.y;
#pragma unroll
  for (int k = 0; k < 4; k++)
    tile[ty + 8*k][tx] = in[(size_t)(r0 + ty + 8*k) * C + c0 + tx];
  __syncthreads();
#pragma unroll
  for (int k = 0; k < 4; k++)
    out[(size_t)(c0 + ty + 8*k) * R + r0 + tx] = f2b(tile[tx][ty + 8*k]);
}

// ---------------- x init: bf16 only --------------------------------------------
__global__ __launch_bounds__(256) void prep_x(const float* __restrict__ h,
                                              u16* __restrict__ xb) {
  int i = blockIdx.x * 256 + threadIdx.x;
  float4 v = ((const float4*)h)[i];
  ushort4 u; u.x = f2b(v.x); u.y = f2b(v.y); u.z = f2b(v.z); u.w = f2b(v.w);
  ((ushort4*)xb)[i] = u;
}

// ---------------- pbias f32 -> bf16 * log2e, INTERLEAVED per 64-block -------------
// Layout within each row's 64-col block: pos n = (c&15)*4 + (c>>4)  (c = col&63).
__global__ __launch_bounds__(256) void prep_pb(const float* __restrict__ pb,
                                               u16* __restrict__ out) {
  const int n0 = (blockIdx.x * 256 + threadIdx.x) * 4;   // output quad base
  const int rowbase = (n0 >> 9) << 9;                    // row * 512
  const int nb = n0 & 511;
  const int blk = (nb >> 6) << 6;                        // 64-block base
  const int lr_ = (nb >> 2) & 15;
  const float* src = pb + rowbase + blk + lr_;
  ushort4 o;
  o.x = f2b(src[0]  * LOG2E);
  o.y = f2b(src[16] * LOG2E);
  o.z = f2b(src[32] * LOG2E);
  o.w = f2b(src[48] * LOG2E);
  ((ushort4*)out)[n0 >> 2] = o;
}

// ---------------- lag-scale table: inv2[b][i][j] = (lag+1)/(9lag+8)*log2e ---------
__global__ __launch_bounds__(256) void prep_inv(const int* __restrict__ ts,
                                                u16* __restrict__ invb) {
  const int b  = blockIdx.x >> 7;        // grid = B*S/4
  const int rg = blockIdx.x & 127;
  const int wid = threadIdx.x >> 6, lane = threadIdx.x & 63;
  const int i = rg * 4 + wid;
  const float ti = (float)ts[b*S_ + i];
  const int nblk = (lane >> 3) * 64;
  const int l8   = (lane & 7) * 8;
  u16 o[8];
#pragma unroll
  for (int e = 0; e < 8; e++) {
    const int no = l8 + e;
    const int j  = nblk + (no & 3) * 16 + ((no >> 2) & 15);
    float lag = fmaxf((ti - (float)ts[b*S_ + j]) * (1.0f/60000.0f), 0.0f);
    float iv  = (lag + 1.0f) * __builtin_amdgcn_rcpf(fmaf(lag, 9.0f, 8.0f)) * LOG2E;
    o[e] = (u16)(int)rintf((iv - 0.16f) * 524288.0f);
  }
  ushort4 w0 = {o[0], o[1], o[2], o[3]}, w1 = {o[4], o[5], o[6], o[7]};
  u16* out = invb + (((size_t)(b*S_ + i)) << 9) + lane*8;
  *(ushort4*)out       = w0;
  *(ushort4*)(out + 4) = w1;
}

// ---------------- GEMM 128x128 tile, BK=64, 2-PHASE double-buffered ---------------
// B-columns staged PERMUTED (LDS row 16b+a <- global col 4a+b within 64-blocks)
// so fragment (j,lr) holds col wn+lr*4+j -> ushort4 epilogue.
// epi: 0 = bf16 (+bias); 2 = bf16 gelu(+bias); 3 = bf16 V-transposed [B,H,DH,S]
__device__ __forceinline__ void gemm_core(
    const u16* __restrict__ A, const u16* __restrict__ BT,
    const int N, const int K,
    const float* __restrict__ bias, u16* __restrict__ outb, const int epi)
{
  __shared__ u16 As0[128*64], Bs0[128*64];
  __shared__ u16 As1[128*64], Bs1[128*64];
  const int tid = threadIdx.x;
  const int wid = tid >> 6, lane = tid & 63;
  const int wm = (wid >> 1) * 64, wn = (wid & 1) * 64;
  const int lr = lane & 15, quad = lane >> 4;
  const int m0 = blockIdx.x * 128, n0 = blockIdx.y * 128;
  const int l7 = lane & 7, l3 = lane >> 3;
  const int cc = (l7 ^ l3) * 8;
  const int f8 = lr & 7;

  f32x4 acc[4][4];
#pragma unroll
  for (int i = 0; i < 4; i++)
#pragma unroll
    for (int j = 0; j < 4; j++) acc[i][j] = (f32x4){0.f, 0.f, 0.f, 0.f};

  const u16* Ag = A  + (size_t)(m0 + wid*16 + l3)*K + cc;
  const u16* Bg = BT + (size_t)(n0 + l3*4 + wid)*K + cc;   // permuted source row
  const int wo = wid * 1024;

  auto STAGE = [&](int k0, u16* AsB, u16* BsB) {
    u16* AsW = AsB + wo;
    u16* BsW = BsB + wo;
    gld16(Ag + k0,                 AsW);
    gld16(Ag + (size_t)8*K + k0,   AsW + 512);
    gld16(Ag + (size_t)64*K + k0,  AsW + 4096);
    gld16(Ag + (size_t)72*K + k0,  AsW + 4608);
    gld16(Bg + k0,                 BsW);
    gld16(Bg + (size_t)32*K + k0,  BsW + 512);
    gld16(Bg + (size_t)64*K + k0,  BsW + 4096);
    gld16(Bg + (size_t)96*K + k0,  BsW + 4608);
  };
  auto COMPUTE = [&](const u16* AsB, const u16* BsB) {
#pragma unroll
    for (int kh = 0; kh < 2; kh++) {
      bf16x8 af[4], bfr[4];
#pragma unroll
      for (int i = 0; i < 4; i++)
        af[i]  = *(const bf16x8*)(AsB + (wm + i*16 + lr)*64 + (((kh*4 + quad) ^ f8) * 8));
#pragma unroll
      for (int j = 0; j < 4; j++)
        bfr[j] = *(const bf16x8*)(BsB + (wn + j*16 + lr)*64 + (((kh*4 + quad) ^ f8) * 8));
#pragma unroll
      for (int i = 0; i < 4; i++)
#pragma unroll
        for (int j = 0; j < 4; j++)
          acc[i][j] = mfma16(af[i], bfr[j], acc[i][j]);
    }
  };

  const int NT = K >> 6;                 // even (8 or 32)
  STAGE(0, As0, Bs0);
  __syncthreads();
  for (int t = 0; t < NT; t += 2) {
    STAGE((t + 1) << 6, As1, Bs1);
    COMPUTE(As0, Bs0);
    __syncthreads();
    if (t + 2 < NT) STAGE((t + 2) << 6, As0, Bs0);
    COMPUTE(As1, Bs1);
    __syncthreads();
  }

  const int nb = n0 + wn + lr*4;
  float4 b4 = *(const float4*)(bias + nb);
  float bn[4] = {b4.x, b4.y, b4.z, b4.w};

  if (epi == 3) {
#pragma unroll
    for (int i = 0; i < 4; i++) {
      const int m = m0 + wm + i*16 + quad*4;
      const int bb_ = m >> 9, sr = m & 511;
#pragma unroll
      for (int j = 0; j < 4; j++) {
        const int n = nb + j;
        const int hh = n >> 6, dd = n & 63;
        ushort4 o;
        o.x = f2b(acc[i][j][0] + bn[j]);
        o.y = f2b(acc[i][j][1] + bn[j]);
        o.z = f2b(acc[i][j][2] + bn[j]);
        o.w = f2b(acc[i][j][3] + bn[j]);
        *(ushort4*)(outb + (((size_t)((bb_*H_ + hh)*DH_ + dd)) << 9) + sr) = o;
      }
    }
  } else if (epi == 2) {
#pragma unroll
    for (int i = 0; i < 4; i++) {
#pragma unroll
      for (int r = 0; r < 4; r++) {
        const size_t m = (size_t)(m0 + wm + i*16 + quad*4 + r);
        ushort4 o;
        o.x = f2b(gelu_fast(acc[i][0][r] + bn[0]));
        o.y = f2b(gelu_fast(acc[i][1][r] + bn[1]));
        o.z = f2b(gelu_fast(acc[i][2][r] + bn[2]));
        o.w = f2b(gelu_fast(acc[i][3][r] + bn[3]));
        *(ushort4*)(outb + m*N + nb) = o;
      }
    }
  } else {
#pragma unroll
    for (int i = 0; i < 4; i++) {
#pragma unroll
      for (int r = 0; r < 4; r++) {
        const size_t m = (size_t)(m0 + wm + i*16 + quad*4 + r);
        ushort4 o;
        o.x = f2b(acc[i][0][r] + bn[0]);
        o.y = f2b(acc[i][1][r] + bn[1]);
        o.z = f2b(acc[i][2][r] + bn[2]);
        o.w = f2b(acc[i][3][r] + bn[3]);
        *(ushort4*)(outb + m*N + nb) = o;
      }
    }
  }
}

__global__ __launch_bounds__(256) void gemm_kernel(
    const u16* A, const u16* BT, int N, int K,
    const float* bias, u16* outb, int epi)
{
  gemm_core(A, BT, N, K, bias, outb, epi);
}

__global__ __launch_bounds__(256) void gemm_qkv_kernel(
    const u16* A, const u16* BTq, size_t zstride, int K,
    const float* b0, const float* b1, const float* b2,
    u16* out0, u16* out1, u16* out2)
{
  const int z = blockIdx.z;
  const u16* BT = BTq + (size_t)z * zstride;
  const float* bias = (z == 0) ? b0 : (z == 1) ? b1 : b2;
  u16* outb = (z == 0) ? out0 : (z == 1) ? out1 : out2;
  gemm_core(A, BT, 512, K, bias, outb, (z == 2) ? 3 : 0);
}

// ---------------- fused GEMM(64x512) + residual + LayerNorm -----------------------
// out[m,:] = LN(A[m,:]@B + bias + res[m,:]) * g + beta; bf16 out (+f32 out if outf).
// Full output row per block -> LN reduce never leaves the block; kills the
// yf f32 roundtrip (80MB -> 16MB per pair). 8 waves (2 row-grp x 4 col-grp),
// 2-phase dbuf, LDS 144KB, grid = M/64 = 256 blocks (1/CU).
__global__ __launch_bounds__(512, 2) void gemm_ln_kernel(
    const u16* __restrict__ A, const u16* __restrict__ BT, const int K,
    const float* __restrict__ bias, const u16* __restrict__ resb,
    const float* __restrict__ g, const float* __restrict__ bta,
    float* __restrict__ outf, u16* __restrict__ outb)
{
  __shared__ u16 As0[64*64],  As1[64*64];     // 8KB each
  __shared__ u16 Bs0[512*64], Bs1[512*64];    // 64KB each
  float (*red)[8] = (float(*)[8])(void*)As0;  // 2KB alias; As0 dead after K-loop
  const int tid = threadIdx.x;
  const int wid = tid >> 6, lane = tid & 63;
  const int wr = wid >> 2, wc = wid & 3;
  const int wm = wr * 32;
  const int lr = lane & 15, quad = lane >> 4;
  const int m0 = blockIdx.x * 64;
  const int l7 = lane & 7, l3 = lane >> 3;
  const int cc = (l7 ^ l3) * 8;
  const int f8 = lr & 7;

  f32x4 acc[2][8];
#pragma unroll
  for (int i = 0; i < 2; i++)
#pragma unroll
    for (int j = 0; j < 8; j++) acc[i][j] = (f32x4){0.f, 0.f, 0.f, 0.f};

  // A: wave w stages rows w*8+l3 (1 load). B: wave w stages 64-block w (8 loads),
  // PERMUTED source row (LDS row 16b+a <- col 4a+b): per-ld row offsets
  // {0,32,1,33,2,34,3,35} relative to w*64 + 4*l3.
  const u16* Ag = A  + (size_t)(m0 + wid*8 + l3)*K + cc;
  const u16* Bg = BT + (size_t)(wid*64 + l3*4)*K + cc;

  auto STAGE = [&](int k0, u16* AsB, u16* BsB) {
    gld16(Ag + k0, AsB + wid*512);
    u16* bw = BsB + wid*4096;
#pragma unroll
    for (int ld = 0; ld < 8; ld++)
      gld16(Bg + (size_t)(32*(ld & 1) + (ld >> 1))*K + k0, bw + ld*512);
  };
  auto COMPUTE = [&](const u16* AsB, const u16* BsB) {
#pragma unroll
    for (int kh = 0; kh < 2; kh++) {
      bf16x8 af[2], bfr[8];
#pragma unroll
      for (int i = 0; i < 2; i++)
        af[i]  = *(const bf16x8*)(AsB + (wm + i*16 + lr)*64 + (((kh*4 + quad) ^ f8) * 8));
#pragma unroll
      for (int j = 0; j < 8; j++)
        bfr[j] = *(const bf16x8*)(BsB + (wc*128 + j*16 + lr)*64 + (((kh*4 + quad) ^ f8) * 8));
#pragma unroll
      for (int i = 0; i < 2; i++)
#pragma unroll
        for (int j = 0; j < 8; j++)
          acc[i][j] = mfma16(af[i], bfr[j], acc[i][j]);
    }
  };

  const int NT = K >> 6;                 // 8 (Wo) or 32 (Wf), even
  STAGE(0, As0, Bs0);
  __syncthreads();
  for (int t = 0; t < NT; t += 2) {
    STAGE((t + 1) << 6, As1, Bs1);
    COMPUTE(As0, Bs0);
    __syncthreads();
    if (t + 2 < NT) STAGE((t + 2) << 6, As0, Bs0);
    COMPUTE(As1, Bs1);
    __syncthreads();
  }

  // ---- epilogue: y = acc + bias + residual; row partials -> LDS reduce -> LN ----
  const int c0 = wc*128 + lr*4;          // lane's cols: c0..c0+3 and c0+64..c0+67
  float4 bA = *(const float4*)(bias + c0);
  float4 bB = *(const float4*)(bias + c0 + 64);
  float sum[2][4], ssq[2][4];
#pragma unroll
  for (int i = 0; i < 2; i++) {
#pragma unroll
    for (int r = 0; r < 4; r++) {
      const size_t rowg = (size_t)(m0 + wm + i*16 + quad*4 + r);
      ushort4 q0 = *(const ushort4*)(resb + rowg*D_ + c0);
      ushort4 q1 = *(const ushort4*)(resb + rowg*D_ + c0 + 64);
      acc[i][0][r] += bA.x + b2f(q0.x);
      acc[i][1][r] += bA.y + b2f(q0.y);
      acc[i][2][r] += bA.z + b2f(q0.z);
      acc[i][3][r] += bA.w + b2f(q0.w);
      acc[i][4][r] += bB.x + b2f(q1.x);
      acc[i][5][r] += bB.y + b2f(q1.y);
      acc[i][6][r] += bB.z + b2f(q1.z);
      acc[i][7][r] += bB.w + b2f(q1.w);
      float s = 0.f, q = 0.f;
#pragma unroll
      for (int j = 0; j < 8; j++) { float y = acc[i][j][r]; s += y; q += y*y; }
#pragma unroll
      for (int m = 1; m < 16; m <<= 1) { s += __shfl_xor(s, m); q += __shfl_xor(q, m); }
      sum[i][r] = s; ssq[i][r] = q;
    }
  }
  if (lr == 0) {
#pragma unroll
    for (int i = 0; i < 2; i++)
#pragma unroll
      for (int r = 0; r < 4; r++) {
        const int rl = wm + i*16 + quad*4 + r;
        red[rl][wc*2]     = sum[i][r];
        red[rl][wc*2 + 1] = ssq[i][r];
      }
  }
  __syncthreads();

  float4 gA = *(const float4*)(g + c0);
  float4 gB = *(const float4*)(g + c0 + 64);
  float4 aA = *(const float4*)(bta + c0);
  float4 aB = *(const float4*)(bta + c0 + 64);
  float gg[8] = {gA.x, gA.y, gA.z, gA.w, gB.x, gB.y, gB.z, gB.w};
  float bb[8] = {aA.x, aA.y, aA.z, aA.w, aB.x, aB.y, aB.z, aB.w};
#pragma unroll
  for (int i = 0; i < 2; i++) {
#pragma unroll
    for (int r = 0; r < 4; r++) {
      const int rl = wm + i*16 + quad*4 + r;
      const size_t rowg = (size_t)(m0 + rl);
      float4 p0 = *(const float4*)&red[rl][0];
      float4 p1 = *(const float4*)&red[rl][4];
      const float mu = (p0.x + p0.z + p1.x + p1.z) * (1.0f/512.0f);
      const float eq = (p0.y + p0.w + p1.y + p1.w) * (1.0f/512.0f);
      const float rs = rsqrtf(fmaxf(eq - mu*mu, 0.0f) + 1e-12f);
      float o[8];
#pragma unroll
      for (int j = 0; j < 8; j++) o[j] = (acc[i][j][r] - mu) * rs * gg[j] + bb[j];
      ushort4 w0 = {f2b(o[0]), f2b(o[1]), f2b(o[2]), f2b(o[3])};
      ushort4 w1 = {f2b(o[4]), f2b(o[5]), f2b(o[6]), f2b(o[7])};
      *(ushort4*)(outb + rowg*D_ + c0)      = w0;
      *(ushort4*)(outb + rowg*D_ + c0 + 64) = w1;
      if (outf) {
        float4 f0 = {o[0], o[1], o[2], o[3]}, f1 = {o[4], o[5], o[6], o[7]};
        *(float4*)(outf + rowg*D_ + c0)      = f0;
        *(float4*)(outf + rowg*D_ + c0 + 64) = f1;
      }
    }
  }
}

// ---------------- flash attention; interleaved table b64 reads --------------------
// P exponent: p = 2^(s * inv2 + pb2). LDS: 5 x 8KB = 40960 B -> 4 blocks/CU.
__global__ __launch_bounds__(256, 4) void attn_kernel(
    const u16* __restrict__ qb, const u16* __restrict__ kb, const u16* __restrict__ vt,
    const u16* __restrict__ pb16, const u16* __restrict__ invb, u16* __restrict__ cb)
{
  __shared__ u16 QPs[64*64];                 // Q tile; wave's 16-row slice reused as P
  __shared__ u16 Ks[64*64], Vs[64*64], PBs[64*64], INVs[64*64];
  const int b = blockIdx.x, it = blockIdx.y, h = blockIdx.z;
  const int i0 = it * 64;
  const int tid = threadIdx.x, wid = tid >> 6, lane = tid & 63;
  const int lr = lane & 15, quad = lane >> 4;
  const int l7 = lane & 7, l3 = lane >> 3;
  const int cc = (l7 ^ l3) * 8;
  const int f8 = lr & 7;
  const int rr = wid*8 + l3;

  const u16* qg  = qb + ((size_t)(b*S_ + i0))*D_ + h*DH_;
  const u16* kg  = kb + ((size_t)b*S_)*D_ + h*DH_;
  const u16* vg  = vt + ((size_t)(b*H_ + h)*DH_)*S_;
  const u16* pbg = pb16 + ((size_t)(h*S_ + i0))*S_;
  const u16* ivg = invb + ((size_t)(b*S_ + i0))*S_;

  gld16(qg + (size_t)rr*D_ + cc,        QPs + wid*512);
  gld16(qg + (size_t)(rr+32)*D_ + cc,   QPs + 2048 + wid*512);
  __syncthreads();

  bf16x8 aq0 = *(const bf16x8*)(QPs + (wid*16 + lr)*64 + ((quad ^ f8) * 8));
  bf16x8 aq1 = *(const bf16x8*)(QPs + (wid*16 + lr)*64 + (((quad ^ f8) ^ 4) * 8));
  u16* Pw = QPs + wid*1024;

  f32x4 O[4]; float lacc[4];
#pragma unroll
  for (int dt = 0; dt < 4; dt++) O[dt] = (f32x4){0.f, 0.f, 0.f, 0.f};
#pragma unroll
  for (int r = 0; r < 4; r++) lacc[r] = 0.f;
  const int lrh = lr >> 3;

  for (int t8 = 0; t8 < 8; t8++) {
    const int j0 = t8 * 64;
    gld16(kg + (size_t)(j0+rr)*D_ + cc,       Ks   + wid*512);
    gld16(kg + (size_t)(j0+rr+32)*D_ + cc,    Ks   + 2048 + wid*512);
    gld16(vg + (size_t)rr*S_ + j0 + cc,       Vs   + wid*512);
    gld16(vg + (size_t)(rr+32)*S_ + j0 + cc,  Vs   + 2048 + wid*512);
    gld16(pbg + (size_t)rr*S_ + j0 + cc,      PBs  + wid*512);
    gld16(pbg + (size_t)(rr+32)*S_ + j0 + cc, PBs  + 2048 + wid*512);
    gld16(ivg + (size_t)rr*S_ + j0 + cc,      INVs + wid*512);
    gld16(ivg + (size_t)(rr+32)*S_ + j0 + cc, INVs + 2048 + wid*512);
    __syncthreads();

    f32x4 s[4];
#pragma unroll
    for (int jt = 0; jt < 4; jt++) {
      const u16* kr = Ks + (jt*16 + lr)*64;
      bf16x8 bk0 = *(const bf16x8*)(kr + ((quad ^ f8) * 8));
      bf16x8 bk1 = *(const bf16x8*)(kr + (((quad ^ f8) ^ 4) * 8));
      f32x4 z = (f32x4){0.f, 0.f, 0.f, 0.f};
      z = mfma16(aq0, bk0, z);
      z = mfma16(aq1, bk1, z);
      s[jt] = z;
    }
#pragma unroll
    for (int r = 0; r < 4; r++) {
      const int rowl = quad*4 + r;
      const int r7 = rowl & 7;
      const int tbase = (wid*16 + rowl)*64 + ((((lr >> 1) ^ r7) << 3) | ((lr & 1) << 2));
      ushort4 ivq = *(const ushort4*)(INVs + tbase);
      ushort4 pbq = *(const ushort4*)(PBs + tbase);
      const u16 ive[4] = {ivq.x, ivq.y, ivq.z, ivq.w};
      const u16 pbe[4] = {pbq.x, pbq.y, pbq.z, pbq.w};
      const int pbase = rowl*64;
      float pa = 0.f;
#pragma unroll
      for (int jt = 0; jt < 4; jt++) {
        float iv  = fmaf((float)ive[jt], 0x1p-19f, 0.16f);
        float pbf = b2f(pbe[jt]);
        float p = __builtin_amdgcn_exp2f(fmaf(s[jt][r], iv, pbf));
        pa += p;
        const int idx = (((jt*2 + lrh) ^ r7) * 8) + l7;
        Pw[pbase + idx] = f2b(p);
      }
      lacc[r] += pa;
    }
    bf16x8 ap0 = *(const bf16x8*)(Pw + lr*64 + ((quad ^ f8) * 8));
    bf16x8 ap1 = *(const bf16x8*)(Pw + lr*64 + (((quad ^ f8) ^ 4) * 8));
#pragma unroll
    for (int dt = 0; dt < 4; dt++) {
      const u16* vr = Vs + (dt*16 + lr)*64;
      bf16x8 bv0 = *(const bf16x8*)(vr + ((quad ^ f8) * 8));
      bf16x8 bv1 = *(const bf16x8*)(vr + (((quad ^ f8) ^ 4) * 8));
      O[dt] = mfma16(ap0, bv0, O[dt]);
      O[dt] = mfma16(ap1, bv1, O[dt]);
    }
    __syncthreads();
  }

#pragma unroll
  for (int r = 0; r < 4; r++) {
    float sum = lacc[r];
#pragma unroll
    for (int m = 1; m < 16; m <<= 1) sum += __shfl_xor(sum, m);
    const float inv = __builtin_amdgcn_rcpf(sum);
    const size_t row = (size_t)(b*S_ + i0 + wid*16 + quad*4 + r);
#pragma unroll
    for (int dt = 0; dt < 4; dt++)
      cb[row*D_ + h*DH_ + dt*16 + lr] = f2b(O[dt][r] * inv);
  }
}

// ---------------- orchestration ---------------------------------------------------
extern "C" void kernel_launch(void* const* d_in, const int* in_sizes, int n_in,
                              void* d_out, int out_size, void* d_ws, size_t ws_size,
                              hipStream_t stream)
{
  const float* hidden = (const float*)d_in[0];
  const float* pbias  = (const float*)d_in[1];
  const int*   ts     = (const int*)d_in[2];
  const float* Wq = (const float*)d_in[3];   const float* bq  = (const float*)d_in[4];
  const float* Wk = (const float*)d_in[5];   const float* bk  = (const float*)d_in[6];
  const float* Wv = (const float*)d_in[7];   const float* bv  = (const float*)d_in[8];
  const float* Wo = (const float*)d_in[9];   const float* bo  = (const float*)d_in[10];
  const float* l1g = (const float*)d_in[11]; const float* l1b = (const float*)d_in[12];
  const float* Wi = (const float*)d_in[13];  const float* bi  = (const float*)d_in[14];
  const float* Wf = (const float*)d_in[15];  const float* bfw = (const float*)d_in[16];
  const float* l2g = (const float*)d_in[17]; const float* l2b = (const float*)d_in[18];

  char* w = (char*)d_ws;
  u16* xb    = (u16*)w; w += (size_t)M_*D_*2;
  u16* qb    = (u16*)w; w += (size_t)M_*D_*2;
  u16* kbuf  = (u16*)w; w += (size_t)M_*D_*2;
  u16* vtw   = (u16*)w; w += (size_t)M_*D_*2;
  u16* cbuf  = (u16*)w; w += (size_t)M_*D_*2;
  u16* attnb = (u16*)w; w += (size_t)M_*D_*2;
  u16* WqkvT = (u16*)w; w += (size_t)3*L_*D_*D_*2;
  u16* WoT   = (u16*)w; w += (size_t)L_*D_*D_*2;
  u16* WiT   = (u16*)w; w += (size_t)L_*D_*F_*2;
  u16* WfT   = (u16*)w; w += (size_t)L_*F_*D_*2;
  u16* pbb   = (u16*)w; w += (size_t)H_*S_*S_*2;
  u16* invb  = (u16*)w; w += (size_t)B_*S_*S_*2;
  u16* hb    = qb;   // alias: qb..cbuf = M_*F_ bf16; lifetimes disjoint

  float* x = (float*)d_out;   // written only by the final fused LN

  const size_t WD = (size_t)D_*D_;
  const size_t WF = (size_t)D_*F_;
  dim3 tb(32, 8);

  transpose_w<<<dim3(16,16,L_), tb, 0, stream>>>(Wq, WqkvT,           D_, D_);
  transpose_w<<<dim3(16,16,L_), tb, 0, stream>>>(Wk, WqkvT + L_*WD,   D_, D_);
  transpose_w<<<dim3(16,16,L_), tb, 0, stream>>>(Wv, WqkvT + 2*L_*WD, D_, D_);
  transpose_w<<<dim3(16,16,L_), tb, 0, stream>>>(Wo, WoT,             D_, D_);
  transpose_w<<<dim3(64,16,L_), tb, 0, stream>>>(Wi, WiT,             D_, F_);
  transpose_w<<<dim3(16,64,L_), tb, 0, stream>>>(Wf, WfT,             F_, D_);
  prep_x<<<dim3(8192), dim3(256), 0, stream>>>(hidden, xb);
  prep_pb<<<dim3(H_*S_*S_/1024), dim3(256), 0, stream>>>(pbias, pbb);
  prep_inv<<<dim3(B_*S_/4), dim3(256), 0, stream>>>(ts, invb);

  for (int l = 0; l < L_; l++) {
    gemm_qkv_kernel<<<dim3(128,4,3), dim3(256), 0, stream>>>(
        xb, WqkvT + l*WD, (size_t)L_*WD, D_,
        bq + l*D_, bk + l*D_, bv + l*D_, qb, kbuf, vtw);
    attn_kernel<<<dim3(B_,8,H_), dim3(256), 0, stream>>>(qb, kbuf, vtw, pbb, invb, cbuf);
    gemm_ln_kernel<<<dim3(256), dim3(512), 0, stream>>>(
        cbuf, WoT + l*WD, D_, bo + l*D_, xb,
        l1g + l*D_, l1b + l*D_, (float*)nullptr, attnb);
    gemm_kernel<<<dim3(128,16), dim3(256), 0, stream>>>(
        attnb, WiT + l*WF, F_, D_, bi + l*F_, hb, 2);
    gemm_ln_kernel<<<dim3(256), dim3(512), 0, stream>>>(
        hb, WfT + l*WF, F_, bfw + l*D_, attnb,
        l2g + l*D_, l2b + l*D_, (l == 3) ? x : (float*)nullptr, xb);
  }
}

// Round 6
// 932.758 us; speedup vs baseline: 1.1673x; 1.0495x over previous
//
#include <hip/hip_runtime.h>
#include <stdint.h>

// SAINT encoder: B=32 S=512 D=512 H=8 DH=64 F=2048 L=4
#define B_ 32
#define S_ 512
#define D_ 512
#define H_ 8
#define F_ 2048
#define L_ 4
#define DH_ 64
#define M_ (B_*S_)

typedef unsigned short u16;
typedef float f32x4 __attribute__((ext_vector_type(4)));
typedef short bf16x8 __attribute__((ext_vector_type(8)));

__device__ __forceinline__ u16 f2b(float f) {
  unsigned u = __float_as_uint(f);
  u += 0x7FFFu + ((u >> 16) & 1u);
  return (u16)(u >> 16);
}
__device__ __forceinline__ float b2f(u16 u) {
  return __uint_as_float((unsigned)u << 16);
}
__device__ __forceinline__ void gld16(const void* g, void* l) {
  __builtin_amdgcn_global_load_lds((__attribute__((address_space(1))) void*)(void*)g,
                                   (__attribute__((address_space(3))) void*)l, 16, 0, 0);
}
__device__ __forceinline__ f32x4 mfma16(bf16x8 a, bf16x8 b, f32x4 c) {
  return __builtin_amdgcn_mfma_f32_16x16x32_bf16(a, b, c, 0, 0, 0);
}
// tanh-form GELU (max |err| ~3e-3 vs erf form; renormalized downstream by Wf+LN)
__device__ __forceinline__ float gelu_fast(float x) {
  float z = 0.7978845608028654f * fmaf(0.044715f * x, x * x, x);
  float e = __expf(2.0f * z);
  float t = 1.0f - 2.0f * __builtin_amdgcn_rcpf(e + 1.0f);   // tanh(z)
  return 0.5f * x * (1.0f + t);
}

#define LOG2E 1.4426950408889634f
// counted-vmcnt pipeline primitives (T4): never drain vmcnt(0) mid-loop.
#define VMWAIT(n)  asm volatile("s_waitcnt vmcnt(" #n ")" ::: "memory")
#define LGKM0()    asm volatile("s_waitcnt lgkmcnt(0)" ::: "memory")
#define SBAR()     __builtin_amdgcn_s_barrier()
#define SCHED0()   __builtin_amdgcn_sched_barrier(0)

// ---------------- weight transpose + bf16: W[R][C] f32 -> WT[C][R] bf16 -----------
__global__ __launch_bounds__(256) void transpose_w(const float* __restrict__ in,
                                                   u16* __restrict__ out, int R, int C) {
  __shared__ float tile[32][33];
  const int l = blockIdx.z;
  in  += (size_t)l * R * C;
  out += (size_t)l * R * C;
  const int c0 = blockIdx.x * 32, r0 = blockIdx.y * 32;
  const int tx = threadIdx.x, ty = threadIdx.y;
#pragma unroll
  for (int k = 0; k < 4; k++)
    tile[ty + 8*k][tx] = in[(size_t)(r0 + ty + 8*k) * C + c0 + tx];
  __syncthreads();
#pragma unroll
  for (int k = 0; k < 4; k++)
    out[(size_t)(c0 + ty + 8*k) * R + r0 + tx] = f2b(tile[tx][ty + 8*k]);
}

// ---------------- x init: bf16 only --------------------------------------------
__global__ __launch_bounds__(256) void prep_x(const float* __restrict__ h,
                                              u16* __restrict__ xb) {
  int i = blockIdx.x * 256 + threadIdx.x;
  float4 v = ((const float4*)h)[i];
  ushort4 u; u.x = f2b(v.x); u.y = f2b(v.y); u.z = f2b(v.z); u.w = f2b(v.w);
  ((ushort4*)xb)[i] = u;
}

// ---------------- pbias f32 -> bf16 * log2e, INTERLEAVED per 64-block -------------
// Layout within each row's 64-col block: pos n = (c&15)*4 + (c>>4)  (c = col&63).
__global__ __launch_bounds__(256) void prep_pb(const float* __restrict__ pb,
                                               u16* __restrict__ out) {
  const int n0 = (blockIdx.x * 256 + threadIdx.x) * 4;   // output quad base
  const int rowbase = (n0 >> 9) << 9;                    // row * 512
  const int nb = n0 & 511;
  const int blk = (nb >> 6) << 6;                        // 64-block base
  const int lr_ = (nb >> 2) & 15;
  const float* src = pb + rowbase + blk + lr_;
  ushort4 o;
  o.x = f2b(src[0]  * LOG2E);
  o.y = f2b(src[16] * LOG2E);
  o.z = f2b(src[32] * LOG2E);
  o.w = f2b(src[48] * LOG2E);
  ((ushort4*)out)[n0 >> 2] = o;
}

// ---------------- lag-scale table: inv2[b][i][j] = (lag+1)/(9lag+8)*log2e ---------
__global__ __launch_bounds__(256) void prep_inv(const int* __restrict__ ts,
                                                u16* __restrict__ invb) {
  const int b  = blockIdx.x >> 7;        // grid = B*S/4
  const int rg = blockIdx.x & 127;
  const int wid = threadIdx.x >> 6, lane = threadIdx.x & 63;
  const int i = rg * 4 + wid;
  const float ti = (float)ts[b*S_ + i];
  const int nblk = (lane >> 3) * 64;
  const int l8   = (lane & 7) * 8;
  u16 o[8];
#pragma unroll
  for (int e = 0; e < 8; e++) {
    const int no = l8 + e;
    const int j  = nblk + (no & 3) * 16 + ((no >> 2) & 15);
    float lag = fmaxf((ti - (float)ts[b*S_ + j]) * (1.0f/60000.0f), 0.0f);
    float iv  = (lag + 1.0f) * __builtin_amdgcn_rcpf(fmaf(lag, 9.0f, 8.0f)) * LOG2E;
    o[e] = (u16)(int)rintf((iv - 0.16f) * 524288.0f);
  }
  ushort4 w0 = {o[0], o[1], o[2], o[3]}, w1 = {o[4], o[5], o[6], o[7]};
  u16* out = invb + (((size_t)(b*S_ + i)) << 9) + lane*8;
  *(ushort4*)out       = w0;
  *(ushort4*)(out + 4) = w1;
}

// ---------------- GEMM 128x128 tile, BK=64, dbuf + counted vmcnt ------------------
// Pipeline per K-tile pair: VMWAIT(8) [only cur batch] -> s_barrier -> COMPUTE ->
// lgkmcnt(0) [reads executed] -> s_barrier -> STAGE next into freed buffer.
// Tail uses VMWAIT(0) (with exactly 8 outstanding, VMWAIT(8) would pass w/o wait).
// N,K compile-time -> all strides fold to shifts.
// B-columns staged PERMUTED so fragment (j,lr) holds col wn+lr*4+j -> ushort4 epi.
// epi: 0 = bf16 (+bias); 2 = bf16 gelu(+bias); 3 = bf16 V-transposed [B,H,DH,S]
template<int N, int K>
__device__ __forceinline__ void gemm_core(
    const u16* __restrict__ A, const u16* __restrict__ BT,
    const float* __restrict__ bias, u16* __restrict__ outb, const int epi)
{
  __shared__ u16 As0[128*64], Bs0[128*64];
  __shared__ u16 As1[128*64], Bs1[128*64];
  const int tid = threadIdx.x;
  const int wid = tid >> 6, lane = tid & 63;
  const int wm = (wid >> 1) * 64, wn = (wid & 1) * 64;
  const int lr = lane & 15, quad = lane >> 4;
  const int m0 = blockIdx.x * 128, n0 = blockIdx.y * 128;
  const int l7 = lane & 7, l3 = lane >> 3;
  const int cc = (l7 ^ l3) * 8;
  const int f8 = lr & 7;

  f32x4 acc[4][4];
#pragma unroll
  for (int i = 0; i < 4; i++)
#pragma unroll
    for (int j = 0; j < 4; j++) acc[i][j] = (f32x4){0.f, 0.f, 0.f, 0.f};

  const u16* Ag = A  + (size_t)(m0 + wid*16 + l3)*K + cc;
  const u16* Bg = BT + (size_t)(n0 + l3*4 + wid)*K + cc;   // permuted source row
  const int wo = wid * 1024;

  auto STAGE = [&](int k0, u16* AsB, u16* BsB) {
    u16* AsW = AsB + wo;
    u16* BsW = BsB + wo;
    gld16(Ag + k0,                 AsW);
    gld16(Ag + (size_t)8*K + k0,   AsW + 512);
    gld16(Ag + (size_t)64*K + k0,  AsW + 4096);
    gld16(Ag + (size_t)72*K + k0,  AsW + 4608);
    gld16(Bg + k0,                 BsW);
    gld16(Bg + (size_t)32*K + k0,  BsW + 512);
    gld16(Bg + (size_t)64*K + k0,  BsW + 4096);
    gld16(Bg + (size_t)96*K + k0,  BsW + 4608);
  };
  auto COMPUTE = [&](const u16* AsB, const u16* BsB) {
#pragma unroll
    for (int kh = 0; kh < 2; kh++) {
      bf16x8 af[4], bfr[4];
#pragma unroll
      for (int i = 0; i < 4; i++)
        af[i]  = *(const bf16x8*)(AsB + (wm + i*16 + lr)*64 + (((kh*4 + quad) ^ f8) * 8));
#pragma unroll
      for (int j = 0; j < 4; j++)
        bfr[j] = *(const bf16x8*)(BsB + (wn + j*16 + lr)*64 + (((kh*4 + quad) ^ f8) * 8));
#pragma unroll
      for (int i = 0; i < 4; i++)
#pragma unroll
        for (int j = 0; j < 4; j++)
          acc[i][j] = mfma16(af[i], bfr[j], acc[i][j]);
    }
  };

  constexpr int NT = K >> 6;             // 8 or 32
  STAGE(0, As0, Bs0);
  STAGE(64, As1, Bs1);
  for (int t = 0; t + 2 < NT; t += 2) {
    VMWAIT(8); SBAR(); SCHED0();         // buf0's batch done (buf1 may fly)
    COMPUTE(As0, Bs0);
    LGKM0(); SBAR();                     // all waves' reads of buf0 executed
    STAGE((t + 2) << 6, As0, Bs0);
    VMWAIT(8); SBAR(); SCHED0();
    COMPUTE(As1, Bs1);
    LGKM0(); SBAR();
    STAGE((t + 3) << 6, As1, Bs1);
  }
  // tail: t = NT-2
  VMWAIT(8); SBAR(); SCHED0();
  COMPUTE(As0, Bs0);
  VMWAIT(0); LGKM0(); SBAR(); SCHED0();
  COMPUTE(As1, Bs1);

  const int nb = n0 + wn + lr*4;
  float4 b4 = *(const float4*)(bias + nb);
  float bn[4] = {b4.x, b4.y, b4.z, b4.w};

  if (epi == 3) {
#pragma unroll
    for (int i = 0; i < 4; i++) {
      const int m = m0 + wm + i*16 + quad*4;
      const int bb_ = m >> 9, sr = m & 511;
#pragma unroll
      for (int j = 0; j < 4; j++) {
        const int n = nb + j;
        const int hh = n >> 6, dd = n & 63;
        ushort4 o;
        o.x = f2b(acc[i][j][0] + bn[j]);
        o.y = f2b(acc[i][j][1] + bn[j]);
        o.z = f2b(acc[i][j][2] + bn[j]);
        o.w = f2b(acc[i][j][3] + bn[j]);
        *(ushort4*)(outb + (((size_t)((bb_*H_ + hh)*DH_ + dd)) << 9) + sr) = o;
      }
    }
  } else if (epi == 2) {
#pragma unroll
    for (int i = 0; i < 4; i++) {
#pragma unroll
      for (int r = 0; r < 4; r++) {
        const size_t m = (size_t)(m0 + wm + i*16 + quad*4 + r);
        ushort4 o;
        o.x = f2b(gelu_fast(acc[i][0][r] + bn[0]));
        o.y = f2b(gelu_fast(acc[i][1][r] + bn[1]));
        o.z = f2b(gelu_fast(acc[i][2][r] + bn[2]));
        o.w = f2b(gelu_fast(acc[i][3][r] + bn[3]));
        *(ushort4*)(outb + m*N + nb) = o;
      }
    }
  } else {
#pragma unroll
    for (int i = 0; i < 4; i++) {
#pragma unroll
      for (int r = 0; r < 4; r++) {
        const size_t m = (size_t)(m0 + wm + i*16 + quad*4 + r);
        ushort4 o;
        o.x = f2b(acc[i][0][r] + bn[0]);
        o.y = f2b(acc[i][1][r] + bn[1]);
        o.z = f2b(acc[i][2][r] + bn[2]);
        o.w = f2b(acc[i][3][r] + bn[3]);
        *(ushort4*)(outb + m*N + nb) = o;
      }
    }
  }
}

template<int N, int K>
__global__ __launch_bounds__(256) void gemm_tmpl_kernel(
    const u16* A, const u16* BT, const float* bias, u16* outb, int epi)
{
  gemm_core<N, K>(A, BT, bias, outb, epi);
}

__global__ __launch_bounds__(256) void gemm_qkv_kernel(
    const u16* A, const u16* BTq, size_t zstride,
    const float* b0, const float* b1, const float* b2,
    u16* out0, u16* out1, u16* out2)
{
  const int z = blockIdx.z;
  const u16* BT = BTq + (size_t)z * zstride;
  const float* bias = (z == 0) ? b0 : (z == 1) ? b1 : b2;
  u16* outb = (z == 0) ? out0 : (z == 1) ? out1 : out2;
  gemm_core<512, 512>(A, BT, bias, outb, (z == 2) ? 3 : 0);
}

// ---------------- fused GEMM(64x512) + residual + LayerNorm -----------------------
// out[m,:] = LN(A[m,:]@B + bias + res[m,:]) * g + beta; bf16 out (+f32 out if outf).
// Full output row per block -> LN reduce never leaves the block. 8 waves,
// dbuf + counted vmcnt (9 loads/wave/stage), LDS 144KB, grid = M/64 (1 blk/CU).
template<int K>
__global__ __launch_bounds__(512, 2) void gemm_ln_kernel(
    const u16* __restrict__ A, const u16* __restrict__ BT,
    const float* __restrict__ bias, const u16* __restrict__ resb,
    const float* __restrict__ g, const float* __restrict__ bta,
    float* __restrict__ outf, u16* __restrict__ outb)
{
  __shared__ u16 As0[64*64],  As1[64*64];     // 8KB each
  __shared__ u16 Bs0[512*64], Bs1[512*64];    // 64KB each
  float (*red)[8] = (float(*)[8])(void*)As0;  // 2KB alias; As0 dead after K-loop
  const int tid = threadIdx.x;
  const int wid = tid >> 6, lane = tid & 63;
  const int wr = wid >> 2, wc = wid & 3;
  const int wm = wr * 32;
  const int lr = lane & 15, quad = lane >> 4;
  const int m0 = blockIdx.x * 64;
  const int l7 = lane & 7, l3 = lane >> 3;
  const int cc = (l7 ^ l3) * 8;
  const int f8 = lr & 7;

  f32x4 acc[2][8];
#pragma unroll
  for (int i = 0; i < 2; i++)
#pragma unroll
    for (int j = 0; j < 8; j++) acc[i][j] = (f32x4){0.f, 0.f, 0.f, 0.f};

  const u16* Ag = A  + (size_t)(m0 + wid*8 + l3)*K + cc;
  const u16* Bg = BT + (size_t)(wid*64 + l3*4)*K + cc;

  auto STAGE = [&](int k0, u16* AsB, u16* BsB) {
    gld16(Ag + k0, AsB + wid*512);
    u16* bw = BsB + wid*4096;
#pragma unroll
    for (int ld = 0; ld < 8; ld++)
      gld16(Bg + (size_t)(32*(ld & 1) + (ld >> 1))*K + k0, bw + ld*512);
  };
  auto COMPUTE = [&](const u16* AsB, const u16* BsB) {
#pragma unroll
    for (int kh = 0; kh < 2; kh++) {
      bf16x8 af[2], bfr[8];
#pragma unroll
      for (int i = 0; i < 2; i++)
        af[i]  = *(const bf16x8*)(AsB + (wm + i*16 + lr)*64 + (((kh*4 + quad) ^ f8) * 8));
#pragma unroll
      for (int j = 0; j < 8; j++)
        bfr[j] = *(const bf16x8*)(BsB + (wc*128 + j*16 + lr)*64 + (((kh*4 + quad) ^ f8) * 8));
#pragma unroll
      for (int i = 0; i < 2; i++)
#pragma unroll
        for (int j = 0; j < 8; j++)
          acc[i][j] = mfma16(af[i], bfr[j], acc[i][j]);
    }
  };

  constexpr int NT = K >> 6;             // 8 (Wo) or 32 (Wf)
  STAGE(0, As0, Bs0);
  STAGE(64, As1, Bs1);
  for (int t = 0; t + 2 < NT; t += 2) {
    VMWAIT(9); SBAR(); SCHED0();
    COMPUTE(As0, Bs0);
    LGKM0(); SBAR();
    STAGE((t + 2) << 6, As0, Bs0);
    VMWAIT(9); SBAR(); SCHED0();
    COMPUTE(As1, Bs1);
    LGKM0(); SBAR();
    STAGE((t + 3) << 6, As1, Bs1);
  }
  VMWAIT(9); SBAR(); SCHED0();
  COMPUTE(As0, Bs0);
  VMWAIT(0); LGKM0(); SBAR(); SCHED0();
  COMPUTE(As1, Bs1);
  __syncthreads();                       // before red[] aliases As0

  // ---- epilogue: y = acc + bias + residual; row partials -> LDS reduce -> LN ----
  const int c0 = wc*128 + lr*4;          // lane's cols: c0..c0+3 and c0+64..c0+67
  float4 bA = *(const float4*)(bias + c0);
  float4 bB = *(const float4*)(bias + c0 + 64);
  float sum[2][4], ssq[2][4];
#pragma unroll
  for (int i = 0; i < 2; i++) {
#pragma unroll
    for (int r = 0; r < 4; r++) {
      const size_t rowg = (size_t)(m0 + wm + i*16 + quad*4 + r);
      ushort4 q0 = *(const ushort4*)(resb + rowg*D_ + c0);
      ushort4 q1 = *(const ushort4*)(resb + rowg*D_ + c0 + 64);
      acc[i][0][r] += bA.x + b2f(q0.x);
      acc[i][1][r] += bA.y + b2f(q0.y);
      acc[i][2][r] += bA.z + b2f(q0.z);
      acc[i][3][r] += bA.w + b2f(q0.w);
      acc[i][4][r] += bB.x + b2f(q1.x);
      acc[i][5][r] += bB.y + b2f(q1.y);
      acc[i][6][r] += bB.z + b2f(q1.z);
      acc[i][7][r] += bB.w + b2f(q1.w);
      float s = 0.f, q = 0.f;
#pragma unroll
      for (int j = 0; j < 8; j++) { float y = acc[i][j][r]; s += y; q += y*y; }
#pragma unroll
      for (int m = 1; m < 16; m <<= 1) { s += __shfl_xor(s, m); q += __shfl_xor(q, m); }
      sum[i][r] = s; ssq[i][r] = q;
    }
  }
  if (lr == 0) {
#pragma unroll
    for (int i = 0; i < 2; i++)
#pragma unroll
      for (int r = 0; r < 4; r++) {
        const int rl = wm + i*16 + quad*4 + r;
        red[rl][wc*2]     = sum[i][r];
        red[rl][wc*2 + 1] = ssq[i][r];
      }
  }
  __syncthreads();

  float4 gA = *(const float4*)(g + c0);
  float4 gB = *(const float4*)(g + c0 + 64);
  float4 aA = *(const float4*)(bta + c0);
  float4 aB = *(const float4*)(bta + c0 + 64);
  float gg[8] = {gA.x, gA.y, gA.z, gA.w, gB.x, gB.y, gB.z, gB.w};
  float bb[8] = {aA.x, aA.y, aA.z, aA.w, aB.x, aB.y, aB.z, aB.w};
#pragma unroll
  for (int i = 0; i < 2; i++) {
#pragma unroll
    for (int r = 0; r < 4; r++) {
      const int rl = wm + i*16 + quad*4 + r;
      const size_t rowg = (size_t)(m0 + rl);
      float4 p0 = *(const float4*)&red[rl][0];
      float4 p1 = *(const float4*)&red[rl][4];
      const float mu = (p0.x + p0.z + p1.x + p1.z) * (1.0f/512.0f);
      const float eq = (p0.y + p0.w + p1.y + p1.w) * (1.0f/512.0f);
      const float rs = rsqrtf(fmaxf(eq - mu*mu, 0.0f) + 1e-12f);
      float o[8];
#pragma unroll
      for (int j = 0; j < 8; j++) o[j] = (acc[i][j][r] - mu) * rs * gg[j] + bb[j];
      ushort4 w0 = {f2b(o[0]), f2b(o[1]), f2b(o[2]), f2b(o[3])};
      ushort4 w1 = {f2b(o[4]), f2b(o[5]), f2b(o[6]), f2b(o[7])};
      *(ushort4*)(outb + rowg*D_ + c0)      = w0;
      *(ushort4*)(outb + rowg*D_ + c0 + 64) = w1;
      if (outf) {
        float4 f0 = {o[0], o[1], o[2], o[3]}, f1 = {o[4], o[5], o[6], o[7]};
        *(float4*)(outf + rowg*D_ + c0)      = f0;
        *(float4*)(outf + rowg*D_ + c0 + 64) = f1;
      }
    }
  }
}

// ---------------- flash attention; interleaved table b64 reads --------------------
// P exponent: p = 2^(s * inv2 + pb2). LDS: 5 x 8KB = 40960 B -> 4 blocks/CU.
__global__ __launch_bounds__(256, 4) void attn_kernel(
    const u16* __restrict__ qb, const u16* __restrict__ kb, const u16* __restrict__ vt,
    const u16* __restrict__ pb16, const u16* __restrict__ invb, u16* __restrict__ cb)
{
  __shared__ u16 QPs[64*64];                 // Q tile; wave's 16-row slice reused as P
  __shared__ u16 Ks[64*64], Vs[64*64], PBs[64*64], INVs[64*64];
  const int b = blockIdx.x, it = blockIdx.y, h = blockIdx.z;
  const int i0 = it * 64;
  const int tid = threadIdx.x, wid = tid >> 6, lane = tid & 63;
  const int lr = lane & 15, quad = lane >> 4;
  const int l7 = lane & 7, l3 = lane >> 3;
  const int cc = (l7 ^ l3) * 8;
  const int f8 = lr & 7;
  const int rr = wid*8 + l3;

  const u16* qg  = qb + ((size_t)(b*S_ + i0))*D_ + h*DH_;
  const u16* kg  = kb + ((size_t)b*S_)*D_ + h*DH_;
  const u16* vg  = vt + ((size_t)(b*H_ + h)*DH_)*S_;
  const u16* pbg = pb16 + ((size_t)(h*S_ + i0))*S_;
  const u16* ivg = invb + ((size_t)(b*S_ + i0))*S_;

  gld16(qg + (size_t)rr*D_ + cc,        QPs + wid*512);
  gld16(qg + (size_t)(rr+32)*D_ + cc,   QPs + 2048 + wid*512);
  __syncthreads();

  bf16x8 aq0 = *(const bf16x8*)(QPs + (wid*16 + lr)*64 + ((quad ^ f8) * 8));
  bf16x8 aq1 = *(const bf16x8*)(QPs + (wid*16 + lr)*64 + (((quad ^ f8) ^ 4) * 8));
  u16* Pw = QPs + wid*1024;

  f32x4 O[4]; float lacc[4];
#pragma unroll
  for (int dt = 0; dt < 4; dt++) O[dt] = (f32x4){0.f, 0.f, 0.f, 0.f};
#pragma unroll
  for (int r = 0; r < 4; r++) lacc[r] = 0.f;
  const int lrh = lr >> 3;

  for (int t8 = 0; t8 < 8; t8++) {
    const int j0 = t8 * 64;
    gld16(kg + (size_t)(j0+rr)*D_ + cc,       Ks   + wid*512);
    gld16(kg + (size_t)(j0+rr+32)*D_ + cc,    Ks   + 2048 + wid*512);
    gld16(vg + (size_t)rr*S_ + j0 + cc,       Vs   + wid*512);
    gld16(vg + (size_t)(rr+32)*S_ + j0 + cc,  Vs   + 2048 + wid*512);
    gld16(pbg + (size_t)rr*S_ + j0 + cc,      PBs  + wid*512);
    gld16(pbg + (size_t)(rr+32)*S_ + j0 + cc, PBs  + 2048 + wid*512);
    gld16(ivg + (size_t)rr*S_ + j0 + cc,      INVs + wid*512);
    gld16(ivg + (size_t)(rr+32)*S_ + j0 + cc, INVs + 2048 + wid*512);
    __syncthreads();

    f32x4 s[4];
#pragma unroll
    for (int jt = 0; jt < 4; jt++) {
      const u16* kr = Ks + (jt*16 + lr)*64;
      bf16x8 bk0 = *(const bf16x8*)(kr + ((quad ^ f8) * 8));
      bf16x8 bk1 = *(const bf16x8*)(kr + (((quad ^ f8) ^ 4) * 8));
      f32x4 z = (f32x4){0.f, 0.f, 0.f, 0.f};
      z = mfma16(aq0, bk0, z);
      z = mfma16(aq1, bk1, z);
      s[jt] = z;
    }
#pragma unroll
    for (int r = 0; r < 4; r++) {
      const int rowl = quad*4 + r;
      const int r7 = rowl & 7;
      const int tbase = (wid*16 + rowl)*64 + ((((lr >> 1) ^ r7) << 3) | ((lr & 1) << 2));
      ushort4 ivq = *(const ushort4*)(INVs + tbase);
      ushort4 pbq = *(const ushort4*)(PBs + tbase);
      const u16 ive[4] = {ivq.x, ivq.y, ivq.z, ivq.w};
      const u16 pbe[4] = {pbq.x, pbq.y, pbq.z, pbq.w};
      const int pbase = rowl*64;
      float pa = 0.f;
#pragma unroll
      for (int jt = 0; jt < 4; jt++) {
        float iv  = fmaf((float)ive[jt], 0x1p-19f, 0.16f);
        float pbf = b2f(pbe[jt]);
        float p = __builtin_amdgcn_exp2f(fmaf(s[jt][r], iv, pbf));
        pa += p;
        const int idx = (((jt*2 + lrh) ^ r7) * 8) + l7;
        Pw[pbase + idx] = f2b(p);
      }
      lacc[r] += pa;
    }
    bf16x8 ap0 = *(const bf16x8*)(Pw + lr*64 + ((quad ^ f8) * 8));
    bf16x8 ap1 = *(const bf16x8*)(Pw + lr*64 + (((quad ^ f8) ^ 4) * 8));
#pragma unroll
    for (int dt = 0; dt < 4; dt++) {
      const u16* vr = Vs + (dt*16 + lr)*64;
      bf16x8 bv0 = *(const bf16x8*)(vr + ((quad ^ f8) * 8));
      bf16x8 bv1 = *(const bf16x8*)(vr + (((quad ^ f8) ^ 4) * 8));
      O[dt] = mfma16(ap0, bv0, O[dt]);
      O[dt] = mfma16(ap1, bv1, O[dt]);
    }
    __syncthreads();
  }

#pragma unroll
  for (int r = 0; r < 4; r++) {
    float sum = lacc[r];
#pragma unroll
    for (int m = 1; m < 16; m <<= 1) sum += __shfl_xor(sum, m);
    const float inv = __builtin_amdgcn_rcpf(sum);
    const size_t row = (size_t)(b*S_ + i0 + wid*16 + quad*4 + r);
#pragma unroll
    for (int dt = 0; dt < 4; dt++)
      cb[row*D_ + h*DH_ + dt*16 + lr] = f2b(O[dt][r] * inv);
  }
}

// ---------------- orchestration ---------------------------------------------------
extern "C" void kernel_launch(void* const* d_in, const int* in_sizes, int n_in,
                              void* d_out, int out_size, void* d_ws, size_t ws_size,
                              hipStream_t stream)
{
  const float* hidden = (const float*)d_in[0];
  const float* pbias  = (const float*)d_in[1];
  const int*   ts     = (const int*)d_in[2];
  const float* Wq = (const float*)d_in[3];   const float* bq  = (const float*)d_in[4];
  const float* Wk = (const float*)d_in[5];   const float* bk  = (const float*)d_in[6];
  const float* Wv = (const float*)d_in[7];   const float* bv  = (const float*)d_in[8];
  const float* Wo = (const float*)d_in[9];   const float* bo  = (const float*)d_in[10];
  const float* l1g = (const float*)d_in[11]; const float* l1b = (const float*)d_in[12];
  const float* Wi = (const float*)d_in[13];  const float* bi  = (const float*)d_in[14];
  const float* Wf = (const float*)d_in[15];  const float* bfw = (const float*)d_in[16];
  const float* l2g = (const float*)d_in[17]; const float* l2b = (const float*)d_in[18];

  char* w = (char*)d_ws;
  u16* xb    = (u16*)w; w += (size_t)M_*D_*2;
  u16* qb    = (u16*)w; w += (size_t)M_*D_*2;
  u16* kbuf  = (u16*)w; w += (size_t)M_*D_*2;
  u16* vtw   = (u16*)w; w += (size_t)M_*D_*2;
  u16* cbuf  = (u16*)w; w += (size_t)M_*D_*2;
  u16* attnb = (u16*)w; w += (size_t)M_*D_*2;
  u16* WqkvT = (u16*)w; w += (size_t)3*L_*D_*D_*2;
  u16* WoT   = (u16*)w; w += (size_t)L_*D_*D_*2;
  u16* WiT   = (u16*)w; w += (size_t)L_*D_*F_*2;
  u16* WfT   = (u16*)w; w += (size_t)L_*F_*D_*2;
  u16* pbb   = (u16*)w; w += (size_t)H_*S_*S_*2;
  u16* invb  = (u16*)w; w += (size_t)B_*S_*S_*2;
  u16* hb    = qb;   // alias: qb..cbuf = M_*F_ bf16; lifetimes disjoint

  float* x = (float*)d_out;   // written only by the final fused LN

  const size_t WD = (size_t)D_*D_;
  const size_t WF = (size_t)D_*F_;
  dim3 tb(32, 8);

  transpose_w<<<dim3(16,16,L_), tb, 0, stream>>>(Wq, WqkvT,           D_, D_);
  transpose_w<<<dim3(16,16,L_), tb, 0, stream>>>(Wk, WqkvT + L_*WD,   D_, D_);
  transpose_w<<<dim3(16,16,L_), tb, 0, stream>>>(Wv, WqkvT + 2*L_*WD, D_, D_);
  transpose_w<<<dim3(16,16,L_), tb, 0, stream>>>(Wo, WoT,             D_, D_);
  transpose_w<<<dim3(64,16,L_), tb, 0, stream>>>(Wi, WiT,             D_, F_);
  transpose_w<<<dim3(16,64,L_), tb, 0, stream>>>(Wf, WfT,             F_, D_);
  prep_x<<<dim3(8192), dim3(256), 0, stream>>>(hidden, xb);
  prep_pb<<<dim3(H_*S_*S_/1024), dim3(256), 0, stream>>>(pbias, pbb);
  prep_inv<<<dim3(B_*S_/4), dim3(256), 0, stream>>>(ts, invb);

  for (int l = 0; l < L_; l++) {
    gemm_qkv_kernel<<<dim3(128,4,3), dim3(256), 0, stream>>>(
        xb, WqkvT + l*WD, (size_t)L_*WD,
        bq + l*D_, bk + l*D_, bv + l*D_, qb, kbuf, vtw);
    attn_kernel<<<dim3(B_,8,H_), dim3(256), 0, stream>>>(qb, kbuf, vtw, pbb, invb, cbuf);
    gemm_ln_kernel<512><<<dim3(256), dim3(512), 0, stream>>>(
        cbuf, WoT + l*WD, bo + l*D_, xb,
        l1g + l*D_, l1b + l*D_, (float*)nullptr, attnb);
    gemm_tmpl_kernel<2048,512><<<dim3(128,16), dim3(256), 0, stream>>>(
        attnb, WiT + l*WF, bi + l*F_, hb, 2);
    gemm_ln_kernel<2048><<<dim3(256), dim3(512), 0, stream>>>(
        hb, WfT + l*WF, bfw + l*D_, attnb,
        l2g + l*D_, l2b + l*D_, (l == 3) ? x : (float*)nullptr, xb);
  }
}